// Round 3
// baseline (385.234 us; speedup 1.0000x reference)
//
#include <hip/hip_runtime.h>
#include <hip/hip_bf16.h>
#include <cstdint>
#include <cstddef>

#define B_ 2
#define S_ 2048
#define D_ 2048
#define H_ 32
#define KVH_ 8
#define HD_ 64
#define PROJN 3072   // Q_OUT(2048) + 2*KV_OUT(512)

typedef unsigned short u16;
typedef __attribute__((ext_vector_type(8))) short short8;
typedef __attribute__((ext_vector_type(4))) float f32x4;

__device__ __forceinline__ u16 f2bf(float f) {
  __hip_bfloat16 h = __float2bfloat16(f);
  return *reinterpret_cast<u16*>(&h);
}

#define GLDS16(g, l)                                                           \
  __builtin_amdgcn_global_load_lds(                                            \
      (const __attribute__((address_space(1))) void*)(g),                      \
      (__attribute__((address_space(3))) void*)(l), 16, 0, 0)

// ---------------- pack f32 -> bf16 ----------------
__global__ __launch_bounds__(256) void pack_bf16(const float* __restrict__ in,
                                                 u16* __restrict__ out, int n) {
  int i = (blockIdx.x * 256 + threadIdx.x) * 8;
  if (i >= n) return;
  const float4* p = reinterpret_cast<const float4*>(in + i);
  float4 a = p[0], b = p[1];
  union { short8 v; u16 u[8]; } r;
  r.u[0] = f2bf(a.x); r.u[1] = f2bf(a.y); r.u[2] = f2bf(a.z); r.u[3] = f2bf(a.w);
  r.u[4] = f2bf(b.x); r.u[5] = f2bf(b.y); r.u[6] = f2bf(b.z); r.u[7] = f2bf(b.w);
  *reinterpret_cast<short8*>(out + i) = r.v;
}

// ---------------- rope cos/sin table ----------------
__global__ __launch_bounds__(256) void rope_table(float* __restrict__ tc,
                                                  float* __restrict__ ts) {
  int i = blockIdx.x * 256 + threadIdx.x;  // S_*32
  int s = i >> 5, j = i & 31;
  float e = (float)(2 * j) / 64.0f;
  float inv_freq = 1.0f / powf(10000.0f, e);
  float ang = (float)s * inv_freq;
  tc[i] = cosf(ang);
  ts[i] = sinf(ang);
}

// ---------------- bf16 GEMM: C[M,N] = A[M,K] * Bw[N,K]^T ----------------
__global__ __launch_bounds__(256) void gemm_bt(const u16* __restrict__ A,
                                               const u16* __restrict__ Bw,
                                               float* __restrict__ C, int M,
                                               int N, int K) {
  __shared__ u16 As[128 * 64];
  __shared__ u16 Bs[128 * 64];
  const int tid = threadIdx.x;
  const int lane = tid & 63;
  const int wave = tid >> 6;
  const int ntile = N >> 7;
  const int m0 = (blockIdx.x / ntile) << 7;
  const int n0 = (blockIdx.x % ntile) << 7;
  const int wr = (wave >> 1) << 6;
  const int wc = (wave & 1) << 6;
  const int arow = lane & 15;
  const int kgrp = lane >> 4;

  const f32x4 zero4 = {0.f, 0.f, 0.f, 0.f};
  f32x4 acc[4][4];
#pragma unroll
  for (int m = 0; m < 4; m++)
#pragma unroll
    for (int n = 0; n < 4; n++) acc[m][n] = zero4;

  int srow[4], sslot[4];
#pragma unroll
  for (int i = 0; i < 4; i++) {
    int c = i * 256 + tid;
    srow[i] = c >> 3;
    sslot[i] = (c & 7) ^ (srow[i] & 7);  // inverse-swizzled source slot
  }

  auto stage = [&](int kt) {
    const int k0 = kt << 6;
#pragma unroll
    for (int i = 0; i < 4; i++) {
      const u16* ga = A + (size_t)(m0 + srow[i]) * K + k0 + sslot[i] * 8;
      GLDS16(ga, As + (i * 256 + tid) * 8);
    }
#pragma unroll
    for (int i = 0; i < 4; i++) {
      const u16* gb = Bw + (size_t)(n0 + srow[i]) * K + k0 + sslot[i] * 8;
      GLDS16(gb, Bs + (i * 256 + tid) * 8);
    }
  };

  const int KT = K >> 6;
  stage(0);
  for (int kt = 0;; kt++) {
    __syncthreads();  // staging drained (compiler emits vmcnt(0) before barrier)
#pragma unroll
    for (int ks = 0; ks < 2; ks++) {
      const int sd = ks * 4 + kgrp;
      short8 a[4], b[4];
#pragma unroll
      for (int m = 0; m < 4; m++) {
        int r = wr + m * 16 + arow;
        a[m] = *reinterpret_cast<const short8*>(As + r * 64 + ((sd ^ (r & 7)) << 3));
      }
#pragma unroll
      for (int n = 0; n < 4; n++) {
        int r = wc + n * 16 + arow;
        b[n] = *reinterpret_cast<const short8*>(Bs + r * 64 + ((sd ^ (r & 7)) << 3));
      }
#pragma unroll
      for (int m = 0; m < 4; m++)
#pragma unroll
        for (int n = 0; n < 4; n++)
          acc[m][n] = __builtin_amdgcn_mfma_f32_16x16x32_bf16(a[m], b[n], acc[m][n], 0, 0, 0);
    }
    if (kt + 1 == KT) break;
    __syncthreads();
    stage(kt + 1);
  }

  const int crow = kgrp * 4;
#pragma unroll
  for (int m = 0; m < 4; m++) {
#pragma unroll
    for (int n = 0; n < 4; n++) {
      float* cp = C + (size_t)(m0 + wr + m * 16 + crow) * N + n0 + wc + n * 16 + arow;
#pragma unroll
      for (int r = 0; r < 4; r++) cp[(size_t)r * N] = acc[m][n][r];
    }
  }
}

// ---------------- RoPE + RMSNorm for Q and K ----------------
// one wave per (b, s, head'), head' in [0,40): 0..31 Q heads, 32..39 K heads
__global__ __launch_bounds__(256) void rope_norm(
    const float* __restrict__ proj, const float* __restrict__ tc,
    const float* __restrict__ ts, const float* __restrict__ gain,
    u16* __restrict__ Qn, u16* __restrict__ Kn) {
  int wid = (blockIdx.x * 256 + threadIdx.x) >> 6;  // B_*S_*40 waves
  int lane = threadIdx.x & 63;
  int hh = wid % 40;
  int bs = wid / 40;  // b*S_ + s
  int s = bs & (S_ - 1);
  int b = bs >> 11;
  int off = hh < 32 ? hh * 64 + lane : 2048 + (hh - 32) * 64 + lane;
  float val = proj[(size_t)bs * PROJN + off];
  int j = lane & 31;
  float c = tc[s * 32 + j], sn = ts[s * 32 + j];
  float partner = __shfl_xor(val, 32);
  float out = lane < 32 ? val * c - partner * sn : val * c + partner * sn;
  float ss = out * out;
#pragma unroll
  for (int m = 32; m >= 1; m >>= 1) ss += __shfl_xor(ss, m);
  float inv = rsqrtf(ss * (1.0f / 64.0f) + 1e-6f);
  float g = hh < 32 ? gain[0] : 1.0f;
  u16 ub = f2bf(out * inv * g);
  if (hh < 32)
    Qn[(((size_t)(b * H_ + hh)) * S_ + s) * HD_ + lane] = ub;
  else
    Kn[(((size_t)(b * KVH_ + (hh - 32))) * S_ + s) * HD_ + lane] = ub;
}

// ---------------- V: transpose to (B,KVH,HD,S) bf16 + V_flat f32 output ----------------
__global__ __launch_bounds__(256) void vtrans(const float* __restrict__ proj,
                                              u16* __restrict__ Vt,
                                              float* __restrict__ Vout) {
  __shared__ float tile[64][65];
  const int bid = blockIdx.x;  // B_*KVH_*(S_/64)
  const int st = bid & 31;
  const int s0 = st << 6;
  const int kvh = (bid >> 5) & 7;
  const int b = bid >> 8;
  const int t = threadIdx.x;
  const int sr = t >> 2;
  const int d0 = (t & 3) << 4;
  const float* src = proj + ((size_t)(b * S_ + s0 + sr)) * PROJN + 2560 + kvh * 64 + d0;
  float v[16];
#pragma unroll
  for (int i = 0; i < 16; i += 4) {
    float4 x = *reinterpret_cast<const float4*>(src + i);
    v[i] = x.x; v[i + 1] = x.y; v[i + 2] = x.z; v[i + 3] = x.w;
  }
  // V_flat output: rows h*B+b, 4 repeated heads (scale rsqrt(1+1e-8) == 1.0f exactly)
#pragma unroll
  for (int hh = 0; hh < 4; hh++) {
    int hq = kvh * 4 + hh;
    float* dst = Vout + (((size_t)(hq * B_ + b)) * S_ + s0 + sr) * HD_ + d0;
#pragma unroll
    for (int i = 0; i < 16; i += 4)
      *reinterpret_cast<float4*>(dst + i) = make_float4(v[i], v[i + 1], v[i + 2], v[i + 3]);
  }
#pragma unroll
  for (int i = 0; i < 16; i++) tile[sr][d0 + i] = v[i];
  __syncthreads();
  const int d = t >> 2;
  const int sc = (t & 3) << 4;
  union { short8 v8; u16 u[8]; } o0, o1;
#pragma unroll
  for (int i = 0; i < 8; i++) o0.u[i] = f2bf(tile[sc + i][d]);
#pragma unroll
  for (int i = 0; i < 8; i++) o1.u[i] = f2bf(tile[sc + 8 + i][d]);
  u16* dst = Vt + (((size_t)(b * KVH_ + kvh)) * HD_ + d) * S_ + s0 + sc;
  *reinterpret_cast<short8*>(dst) = o0.v8;
  *reinterpret_cast<short8*>(dst + 8) = o1.v8;
}

// ---------------- flash attention (causal, GQA) ----------------
// grid: B_*H_*(S_/64); 4 waves, each owns 16 q-rows; KV tiles of 64
__global__ __launch_bounds__(256) void attn_fwd(const u16* __restrict__ Qn,
                                                const u16* __restrict__ Kn,
                                                const u16* __restrict__ Vt,
                                                u16* __restrict__ Aout) {
  __shared__ u16 Ks[64 * 64];
  __shared__ u16 Vs[64 * 64];
  __shared__ u16 Ps[4][16 * 64];
  const int bid = blockIdx.x;
  const int qb = bid & 31;
  const int h = (bid >> 5) & 31;
  const int b = bid >> 10;
  const int kvh = h >> 2;
  const int q0 = qb << 6;
  const int tid = threadIdx.x;
  const int lane = tid & 63;
  const int wave = tid >> 6;
  const int arow = lane & 15;
  const int kgrp = lane >> 4;

  const u16* qrow = Qn + (((size_t)(b * H_ + h)) * S_ + q0 + wave * 16 + arow) * HD_;
  short8 qa[2];
  qa[0] = *reinterpret_cast<const short8*>(qrow + kgrp * 8);
  qa[1] = *reinterpret_cast<const short8*>(qrow + 32 + kgrp * 8);

  const f32x4 zero4 = {0.f, 0.f, 0.f, 0.f};
  f32x4 oacc[4];
#pragma unroll
  for (int n = 0; n < 4; n++) oacc[n] = zero4;
  float mrun[4], lrun[4];
#pragma unroll
  for (int r = 0; r < 4; r++) { mrun[r] = -1e30f; lrun[r] = 0.f; }

  const u16* kg = Kn + ((size_t)(b * KVH_ + kvh)) * S_ * HD_;
  const u16* vg = Vt + ((size_t)(b * KVH_ + kvh)) * HD_ * S_;

  const int c0 = tid, c1 = 256 + tid;
  const int r0 = c0 >> 3, sl0 = (c0 & 7) ^ (r0 & 7);
  const int r1 = c1 >> 3, sl1 = (c1 & 7) ^ (r1 & 7);

  u16* pw = Ps[wave];
  const int prow_w = kgrp * 4;

  for (int jt = 0; jt <= qb; jt++) {
    const int j0 = jt << 6;
    __syncthreads();  // previous iteration's reads done
    GLDS16(kg + (size_t)(j0 + r0) * HD_ + sl0 * 8, Ks + c0 * 8);
    GLDS16(kg + (size_t)(j0 + r1) * HD_ + sl1 * 8, Ks + c1 * 8);
    GLDS16(vg + (size_t)r0 * S_ + j0 + sl0 * 8, Vs + c0 * 8);
    GLDS16(vg + (size_t)r1 * S_ + j0 + sl1 * 8, Vs + c1 * 8);
    __syncthreads();

    // QK^T: 16 q-rows x 64 k-cols
    f32x4 sc[4];
#pragma unroll
    for (int n = 0; n < 4; n++) sc[n] = zero4;
#pragma unroll
    for (int ks = 0; ks < 2; ks++) {
      const int sd = ks * 4 + kgrp;
#pragma unroll
      for (int n = 0; n < 4; n++) {
        const int r = n * 16 + arow;
        short8 kf = *reinterpret_cast<const short8*>(Ks + r * 64 + ((sd ^ (r & 7)) << 3));
        sc[n] = __builtin_amdgcn_mfma_f32_16x16x32_bf16(qa[ks], kf, sc[n], 0, 0, 0);
      }
    }

    const int rb = q0 + wave * 16 + prow_w;
    const bool diag = (jt == qb);
    float alpha[4];
#pragma unroll
    for (int n = 0; n < 4; n++) {
      const int cabs = j0 + n * 16 + arow;
#pragma unroll
      for (int r = 0; r < 4; r++) {
        float v = sc[n][r] * 0.125f;  // 1/sqrt(64)
        if (diag && cabs > rb + r) v = -1e30f;
        sc[n][r] = v;
      }
    }
#pragma unroll
    for (int r = 0; r < 4; r++) {
      float mx = fmaxf(fmaxf(sc[0][r], sc[1][r]), fmaxf(sc[2][r], sc[3][r]));
      mx = fmaxf(mx, __shfl_xor(mx, 1));
      mx = fmaxf(mx, __shfl_xor(mx, 2));
      mx = fmaxf(mx, __shfl_xor(mx, 4));
      mx = fmaxf(mx, __shfl_xor(mx, 8));
      const float mn = fmaxf(mrun[r], mx);
      alpha[r] = __expf(mrun[r] - mn);
      mrun[r] = mn;
      float sum = 0.f;
#pragma unroll
      for (int n = 0; n < 4; n++) {
        float p = __expf(sc[n][r] - mn);
        sc[n][r] = p;
        sum += p;
      }
      sum += __shfl_xor(sum, 1);
      sum += __shfl_xor(sum, 2);
      sum += __shfl_xor(sum, 4);
      sum += __shfl_xor(sum, 8);
      lrun[r] = lrun[r] * alpha[r] + sum;
    }
#pragma unroll
    for (int n = 0; n < 4; n++)
#pragma unroll
      for (int r = 0; r < 4; r++) oacc[n][r] *= alpha[r];

    // P (D-layout) -> per-wave LDS (swizzled) -> A-layout fragments
#pragma unroll
    for (int n = 0; n < 4; n++) {
      const int col = n * 16 + arow;
      const int sdp = col >> 3;
#pragma unroll
      for (int r = 0; r < 4; r++) {
        const int row = prow_w + r;
        pw[row * 64 + ((sdp ^ (row & 7)) << 3) + (col & 7)] = f2bf(sc[n][r]);
      }
    }
#pragma unroll
    for (int ks = 0; ks < 2; ks++) {
      const int sd = ks * 4 + kgrp;
      short8 pa = *reinterpret_cast<const short8*>(pw + arow * 64 + ((sd ^ (arow & 7)) << 3));
#pragma unroll
      for (int n = 0; n < 4; n++) {
        const int vr = n * 16 + arow;
        short8 vf = *reinterpret_cast<const short8*>(Vs + vr * 64 + ((sd ^ (vr & 7)) << 3));
        oacc[n] = __builtin_amdgcn_mfma_f32_16x16x32_bf16(pa, vf, oacc[n], 0, 0, 0);
      }
    }
  }

#pragma unroll
  for (int n = 0; n < 4; n++) {
    const int dcol = n * 16 + arow;
#pragma unroll
    for (int r = 0; r < 4; r++) {
      const int row = q0 + wave * 16 + prow_w + r;
      const float o = oacc[n][r] / lrun[r];
      Aout[((size_t)b * S_ + row) * D_ + h * HD_ + dcol] = f2bf(o);
    }
  }
}

// ---------------- launcher ----------------
extern "C" void kernel_launch(void* const* d_in, const int* in_sizes, int n_in,
                              void* d_out, int out_size, void* d_ws,
                              size_t ws_size, hipStream_t stream) {
  const float* x = (const float*)d_in[0];
  const float* wqkv = (const float*)d_in[1];
  const float* wout = (const float*)d_in[2];
  const float* gain = (const float*)d_in[3];

  float* out_attn = (float*)d_out;                       // (B,S,D) f32
  float* out_vflat = out_attn + (size_t)B_ * S_ * D_;    // (H*B,S,HD) f32

  uint8_t* w = (uint8_t*)d_ws;
  u16* xb     = (u16*)(w);                      // 16,777,216 B
  u16* wqkvb  = (u16*)(w + 16777216);           // 12,582,912 B
  u16* woutb  = (u16*)(w + 29360128);           //  8,388,608 B
  float* proj = (float*)(w + 37748736);         // 50,331,648 B
  u16* Qn     = (u16*)(w + 88080384);           // 16,777,216 B
  u16* Kn     = (u16*)(w + 104857600);          //  4,194,304 B
  u16* Vt     = (u16*)(w + 109051904);          //  4,194,304 B
  u16* attnb  = (u16*)(w + 113246208);          // 16,777,216 B
  float* tc   = (float*)(w + 130023424);        //    262,144 B
  float* ts   = (float*)(w + 130285568);        //    262,144 B
  // total: 130,547,712 B

  pack_bf16<<<4096, 256, 0, stream>>>(x, xb, B_ * S_ * D_);
  pack_bf16<<<3072, 256, 0, stream>>>(wqkv, wqkvb, PROJN * D_);
  pack_bf16<<<2048, 256, 0, stream>>>(wout, woutb, D_ * D_);
  rope_table<<<256, 256, 0, stream>>>(tc, ts);

  // proj = x @ w_qkv^T : (4096 x 3072)
  gemm_bt<<<(4096 / 128) * (3072 / 128), 256, 0, stream>>>(xb, wqkvb, proj,
                                                           4096, PROJN, 2048);
  rope_norm<<<(B_ * S_ * 40) / 4, 256, 0, stream>>>(proj, tc, ts, gain, Qn, Kn);
  vtrans<<<B_ * KVH_ * (S_ / 64), 256, 0, stream>>>(proj, Vt, out_vflat);
  attn_fwd<<<B_ * H_ * (S_ / 64), 256, 0, stream>>>(Qn, Kn, Vt, attnb);
  // attn_out = attn @ w_out^T : (4096 x 2048)
  gemm_bt<<<(4096 / 128) * (2048 / 128), 256, 0, stream>>>(attnb, woutb,
                                                           out_attn, 4096,
                                                           2048, 2048);
}

// Round 4
// 358.222 us; speedup vs baseline: 1.0754x; 1.0754x over previous
//
#include <hip/hip_runtime.h>
#include <hip/hip_bf16.h>
#include <cstdint>
#include <cstddef>

#define B_ 2
#define S_ 2048
#define D_ 2048
#define H_ 32
#define KVH_ 8
#define HD_ 64
#define PROJN 3072   // Q_OUT(2048) + 2*KV_OUT(512)

typedef unsigned short u16;
typedef unsigned int u32;
typedef __attribute__((ext_vector_type(8))) short short8;
typedef __attribute__((ext_vector_type(4))) short short4v;
typedef __attribute__((ext_vector_type(4))) float f32x4;

__device__ __forceinline__ u16 f2bf(float f) {
  __hip_bfloat16 h = __float2bfloat16(f);
  return *reinterpret_cast<u16*>(&h);
}

#define GLDS16(g, l)                                                           \
  __builtin_amdgcn_global_load_lds(                                            \
      (const __attribute__((address_space(1))) void*)(g),                      \
      (__attribute__((address_space(3))) void*)(l), 16, 0, 0)

// ---------------- pack f32 -> bf16 ----------------
__global__ __launch_bounds__(256) void pack_bf16(const float* __restrict__ in,
                                                 u16* __restrict__ out, int n) {
  int i = (blockIdx.x * 256 + threadIdx.x) * 8;
  if (i >= n) return;
  const float4* p = reinterpret_cast<const float4*>(in + i);
  float4 a = p[0], b = p[1];
  union { short8 v; u16 u[8]; } r;
  r.u[0] = f2bf(a.x); r.u[1] = f2bf(a.y); r.u[2] = f2bf(a.z); r.u[3] = f2bf(a.w);
  r.u[4] = f2bf(b.x); r.u[5] = f2bf(b.y); r.u[6] = f2bf(b.z); r.u[7] = f2bf(b.w);
  *reinterpret_cast<short8*>(out + i) = r.v;
}

// ---------------- rope cos/sin table ----------------
__global__ __launch_bounds__(256) void rope_table(float* __restrict__ tc,
                                                  float* __restrict__ ts) {
  int i = blockIdx.x * 256 + threadIdx.x;  // S_*32
  int s = i >> 5, j = i & 31;
  float e = (float)(2 * j) / 64.0f;
  float inv_freq = 1.0f / powf(10000.0f, e);
  float ang = (float)s * inv_freq;
  tc[i] = cosf(ang);
  ts[i] = sinf(ang);
}

// ---------------- bf16 GEMM: C[M,N] = A[M,K] * Bw[N,K]^T ----------------
__global__ __launch_bounds__(256) void gemm_bt(const u16* __restrict__ A,
                                               const u16* __restrict__ Bw,
                                               float* __restrict__ C, int M,
                                               int N, int K) {
  __shared__ u16 As[128 * 64];
  __shared__ u16 Bs[128 * 64];
  const int tid = threadIdx.x;
  const int lane = tid & 63;
  const int wave = tid >> 6;
  const int ntile = N >> 7;
  const int m0 = (blockIdx.x / ntile) << 7;
  const int n0 = (blockIdx.x % ntile) << 7;
  const int wr = (wave >> 1) << 6;
  const int wc = (wave & 1) << 6;
  const int arow = lane & 15;
  const int kgrp = lane >> 4;

  const f32x4 zero4 = {0.f, 0.f, 0.f, 0.f};
  f32x4 acc[4][4];
#pragma unroll
  for (int m = 0; m < 4; m++)
#pragma unroll
    for (int n = 0; n < 4; n++) acc[m][n] = zero4;

  int srow[4], sslot[4];
#pragma unroll
  for (int i = 0; i < 4; i++) {
    int c = i * 256 + tid;
    srow[i] = c >> 3;
    sslot[i] = (c & 7) ^ (srow[i] & 7);  // inverse-swizzled source slot
  }

  auto stage = [&](int kt) {
    const int k0 = kt << 6;
#pragma unroll
    for (int i = 0; i < 4; i++) {
      const u16* ga = A + (size_t)(m0 + srow[i]) * K + k0 + sslot[i] * 8;
      GLDS16(ga, As + (i * 256 + tid) * 8);
    }
#pragma unroll
    for (int i = 0; i < 4; i++) {
      const u16* gb = Bw + (size_t)(n0 + srow[i]) * K + k0 + sslot[i] * 8;
      GLDS16(gb, Bs + (i * 256 + tid) * 8);
    }
  };

  const int KT = K >> 6;
  stage(0);
  for (int kt = 0;; kt++) {
    __syncthreads();  // staging drained (compiler emits vmcnt(0) before barrier)
#pragma unroll
    for (int ks = 0; ks < 2; ks++) {
      const int sd = ks * 4 + kgrp;
      short8 a[4], b[4];
#pragma unroll
      for (int m = 0; m < 4; m++) {
        int r = wr + m * 16 + arow;
        a[m] = *reinterpret_cast<const short8*>(As + r * 64 + ((sd ^ (r & 7)) << 3));
      }
#pragma unroll
      for (int n = 0; n < 4; n++) {
        int r = wc + n * 16 + arow;
        b[n] = *reinterpret_cast<const short8*>(Bs + r * 64 + ((sd ^ (r & 7)) << 3));
      }
#pragma unroll
      for (int m = 0; m < 4; m++)
#pragma unroll
        for (int n = 0; n < 4; n++)
          acc[m][n] = __builtin_amdgcn_mfma_f32_16x16x32_bf16(a[m], b[n], acc[m][n], 0, 0, 0);
    }
    if (kt + 1 == KT) break;
    __syncthreads();
    stage(kt + 1);
  }

  const int crow = kgrp * 4;
#pragma unroll
  for (int m = 0; m < 4; m++) {
#pragma unroll
    for (int n = 0; n < 4; n++) {
      float* cp = C + (size_t)(m0 + wr + m * 16 + crow) * N + n0 + wc + n * 16 + arow;
#pragma unroll
      for (int r = 0; r < 4; r++) cp[(size_t)r * N] = acc[m][n][r];
    }
  }
}

// ---------------- RoPE + RMSNorm for Q and K ----------------
// one wave per (b, s, head'), head' in [0,40): 0..31 Q heads, 32..39 K heads
__global__ __launch_bounds__(256) void rope_norm(
    const float* __restrict__ proj, const float* __restrict__ tc,
    const float* __restrict__ ts, const float* __restrict__ gain,
    u16* __restrict__ Qn, u16* __restrict__ Kn) {
  int wid = (blockIdx.x * 256 + threadIdx.x) >> 6;  // B_*S_*40 waves
  int lane = threadIdx.x & 63;
  int hh = wid % 40;
  int bs = wid / 40;  // b*S_ + s
  int s = bs & (S_ - 1);
  int b = bs >> 11;
  int off = hh < 32 ? hh * 64 + lane : 2048 + (hh - 32) * 64 + lane;
  float val = proj[(size_t)bs * PROJN + off];
  int j = lane & 31;
  float c = tc[s * 32 + j], sn = ts[s * 32 + j];
  float partner = __shfl_xor(val, 32);
  float out = lane < 32 ? val * c - partner * sn : val * c + partner * sn;
  float ss = out * out;
#pragma unroll
  for (int m = 32; m >= 1; m >>= 1) ss += __shfl_xor(ss, m);
  float inv = rsqrtf(ss * (1.0f / 64.0f) + 1e-6f);
  float g = hh < 32 ? gain[0] : 1.0f;
  u16 ub = f2bf(out * inv * g);
  if (hh < 32)
    Qn[(((size_t)(b * H_ + hh)) * S_ + s) * HD_ + lane] = ub;
  else
    Kn[(((size_t)(b * KVH_ + (hh - 32))) * S_ + s) * HD_ + lane] = ub;
}

// ---------------- V: transpose to (B,KVH,HD,S) bf16 + V_flat f32 output ----------------
__global__ __launch_bounds__(256) void vtrans(const float* __restrict__ proj,
                                              u16* __restrict__ Vt,
                                              float* __restrict__ Vout) {
  __shared__ float tile[64][65];
  const int bid = blockIdx.x;  // B_*KVH_*(S_/64)
  const int st = bid & 31;
  const int s0 = st << 6;
  const int kvh = (bid >> 5) & 7;
  const int b = bid >> 8;
  const int t = threadIdx.x;
  const int sr = t >> 2;
  const int d0 = (t & 3) << 4;
  const float* src = proj + ((size_t)(b * S_ + s0 + sr)) * PROJN + 2560 + kvh * 64 + d0;
  float v[16];
#pragma unroll
  for (int i = 0; i < 16; i += 4) {
    float4 x = *reinterpret_cast<const float4*>(src + i);
    v[i] = x.x; v[i + 1] = x.y; v[i + 2] = x.z; v[i + 3] = x.w;
  }
  // V_flat output: rows h*B+b, 4 repeated heads (scale rsqrt(1+1e-8) == 1.0f exactly)
#pragma unroll
  for (int hh = 0; hh < 4; hh++) {
    int hq = kvh * 4 + hh;
    float* dst = Vout + (((size_t)(hq * B_ + b)) * S_ + s0 + sr) * HD_ + d0;
#pragma unroll
    for (int i = 0; i < 16; i += 4)
      *reinterpret_cast<float4*>(dst + i) = make_float4(v[i], v[i + 1], v[i + 2], v[i + 3]);
  }
#pragma unroll
  for (int i = 0; i < 16; i++) tile[sr][d0 + i] = v[i];
  __syncthreads();
  const int d = t >> 2;
  const int sc = (t & 3) << 4;
  union { short8 v8; u16 u[8]; } o0, o1;
#pragma unroll
  for (int i = 0; i < 8; i++) o0.u[i] = f2bf(tile[sc + i][d]);
#pragma unroll
  for (int i = 0; i < 8; i++) o1.u[i] = f2bf(tile[sc + 8 + i][d]);
  u16* dst = Vt + (((size_t)(b * KVH_ + kvh)) * HD_ + d) * S_ + s0 + sc;
  *reinterpret_cast<short8*>(dst) = o0.v8;
  *reinterpret_cast<short8*>(dst + 8) = o1.v8;
}

// ---------------- flash attention (causal, GQA) — swapped-operand form ----------------
// grid: B_*H_*(S_/64); 4 waves, each owns 16 q-rows; KV tiles of 64.
// QK^T computed as S^T = mfma(K_frag, Q_frag): lane&15 owns ONE q-row ->
// softmax reduce = per-lane + 2 shfl_xor. PV computed as O^T = mfma(V^T, P^T):
// alpha/lrun stay lane-local. All LDS staging reads byte-identical to the
// validated round-3 kernel.
__global__ __launch_bounds__(256) void attn_fwd(const u16* __restrict__ Qn,
                                                const u16* __restrict__ Kn,
                                                const u16* __restrict__ Vt,
                                                u16* __restrict__ Aout) {
  __shared__ u16 Ks[64 * 64];
  __shared__ u16 Vs[64 * 64];
  __shared__ u16 Ps[4][16 * 64];
  const int bid = blockIdx.x;
  const int qb = bid & 31;
  const int h = (bid >> 5) & 31;
  const int b = bid >> 10;
  const int kvh = h >> 2;
  const int q0 = qb << 6;
  const int tid = threadIdx.x;
  const int lane = tid & 63;
  const int wave = tid >> 6;
  const int ql = lane & 15;   // q-row this lane owns (softmax / O^T N-dim)
  const int g = lane >> 4;    // k-group
  // scale * log2(e): softmax in exp2 domain (identical result)
  const float SCL2E = 0.125f * 1.44269504088896340736f;

  const u16* qrow = Qn + (((size_t)(b * H_ + h)) * S_ + q0 + wave * 16 + ql) * HD_;
  short8 qa[2];
  qa[0] = *reinterpret_cast<const short8*>(qrow + g * 8);
  qa[1] = *reinterpret_cast<const short8*>(qrow + 32 + g * 8);

  const f32x4 zero4 = {0.f, 0.f, 0.f, 0.f};
  f32x4 oacc[4];  // O^T: dn-tile, lane col = own q-row, rows = d = dn*16+4g+reg
#pragma unroll
  for (int n = 0; n < 4; n++) oacc[n] = zero4;
  float mrun = -1e30f, lrun = 0.f;  // lane-scalar (own q-row), log2 domain

  const u16* kg = Kn + ((size_t)(b * KVH_ + kvh)) * S_ * HD_;
  const u16* vg = Vt + ((size_t)(b * KVH_ + kvh)) * HD_ * S_;

  const int c0 = tid, c1 = 256 + tid;
  const int r0 = c0 >> 3, sl0 = (c0 & 7) ^ (r0 & 7);
  const int r1 = c1 >> 3, sl1 = (c1 & 7) ^ (r1 & 7);

  u16* pw = Ps[wave];
  u32* pw32 = reinterpret_cast<u32*>(pw);
  const int rowq = q0 + wave * 16 + ql;  // absolute q-row for mask
  const int xsw2 = (ql & 7) << 2;        // XOR swizzle (u32-index domain)

  for (int jt = 0; jt <= qb; jt++) {
    const int j0 = jt << 6;
    __syncthreads();  // previous iteration's reads done
    GLDS16(kg + (size_t)(j0 + r0) * HD_ + sl0 * 8, Ks + c0 * 8);
    GLDS16(kg + (size_t)(j0 + r1) * HD_ + sl1 * 8, Ks + c1 * 8);
    GLDS16(vg + (size_t)r0 * S_ + j0 + sl0 * 8, Vs + c0 * 8);
    GLDS16(vg + (size_t)r1 * S_ + j0 + sl1 * 8, Vs + c1 * 8);
    __syncthreads();

    // S^T = K·Q^T : lane holds S^T[kpos=16n+4g+r][own q-row]
    f32x4 sc[4];
#pragma unroll
    for (int n = 0; n < 4; n++) sc[n] = zero4;
#pragma unroll
    for (int ks = 0; ks < 2; ks++) {
      const int sd = ks * 4 + g;
#pragma unroll
      for (int n = 0; n < 4; n++) {
        const int r = n * 16 + ql;
        short8 kf = *reinterpret_cast<const short8*>(Ks + r * 64 + ((sd ^ (r & 7)) << 3));
        sc[n] = __builtin_amdgcn_mfma_f32_16x16x32_bf16(kf, qa[ks], sc[n], 0, 0, 0);
      }
    }

    // scale (log2 domain) + causal mask
    const bool diag = (jt == qb);
#pragma unroll
    for (int n = 0; n < 4; n++) {
#pragma unroll
      for (int r = 0; r < 4; r++) {
        float v = sc[n][r] * SCL2E;
        if (diag && (j0 + n * 16 + 4 * g + r) > rowq) v = -1e30f;
        sc[n][r] = v;
      }
    }

    // online softmax — per-lane over 16 values + 2 shfl_xor reduces
    float tmax = fmaxf(fmaxf(fmaxf(sc[0][0], sc[0][1]), fmaxf(sc[0][2], sc[0][3])),
                       fmaxf(fmaxf(sc[1][0], sc[1][1]), fmaxf(sc[1][2], sc[1][3])));
    tmax = fmaxf(tmax,
                 fmaxf(fmaxf(fmaxf(sc[2][0], sc[2][1]), fmaxf(sc[2][2], sc[2][3])),
                       fmaxf(fmaxf(sc[3][0], sc[3][1]), fmaxf(sc[3][2], sc[3][3]))));
    tmax = fmaxf(tmax, __shfl_xor(tmax, 16));
    tmax = fmaxf(tmax, __shfl_xor(tmax, 32));
    const float mnew = fmaxf(mrun, tmax);
    const float alpha = exp2f(mrun - mnew);
    float sum = 0.f;
#pragma unroll
    for (int n = 0; n < 4; n++)
#pragma unroll
      for (int r = 0; r < 4; r++) {
        float p = exp2f(sc[n][r] - mnew);
        sc[n][r] = p;
        sum += p;
      }
    sum += __shfl_xor(sum, 16);
    sum += __shfl_xor(sum, 32);
    lrun = lrun * alpha + sum;
    mrun = mnew;
#pragma unroll
    for (int n = 0; n < 4; n++)
#pragma unroll
      for (int r = 0; r < 4; r++) oacc[n][r] *= alpha;

    // P^T -> per-wave LDS (packed b32, XOR-swizzled) -> B-fragments
#pragma unroll
    for (int n = 0; n < 4; n++) {
      union { u32 w; u16 h[2]; } c01, c23;
      c01.h[0] = f2bf(sc[n][0]); c01.h[1] = f2bf(sc[n][1]);
      c23.h[0] = f2bf(sc[n][2]); c23.h[1] = f2bf(sc[n][3]);
      const int idx = ql * 32 + (((n << 3) + (g << 1)) ^ xsw2);
      pw32[idx] = c01.w;
      pw32[idx + 1] = c23.w;
    }
    short8 pa[2];
#pragma unroll
    for (int ks = 0; ks < 2; ks++)
      pa[ks] = *reinterpret_cast<const short8*>(
          pw + ql * 64 + ((32 * ks + 8 * g) ^ (xsw2 << 1)));

    // O^T += V^T · P^T
#pragma unroll
    for (int ks = 0; ks < 2; ks++) {
      const int sd = ks * 4 + g;
#pragma unroll
      for (int dn = 0; dn < 4; dn++) {
        const int vr = dn * 16 + ql;
        short8 vf = *reinterpret_cast<const short8*>(Vs + vr * 64 + ((sd ^ (vr & 7)) << 3));
        oacc[dn] = __builtin_amdgcn_mfma_f32_16x16x32_bf16(vf, pa[ks], oacc[dn], 0, 0, 0);
      }
    }
  }

  const float il = 1.0f / lrun;
#pragma unroll
  for (int dn = 0; dn < 4; dn++) {
    union { short4v v; u16 u[4]; } o;
#pragma unroll
    for (int r = 0; r < 4; r++) o.u[r] = f2bf(oacc[dn][r] * il);
    u16* dst = Aout + ((size_t)b * S_ + rowq) * D_ + h * HD_ + dn * 16 + 4 * g;
    *reinterpret_cast<short4v*>(dst) = o.v;
  }
}

// ---------------- launcher ----------------
extern "C" void kernel_launch(void* const* d_in, const int* in_sizes, int n_in,
                              void* d_out, int out_size, void* d_ws,
                              size_t ws_size, hipStream_t stream) {
  const float* x = (const float*)d_in[0];
  const float* wqkv = (const float*)d_in[1];
  const float* wout = (const float*)d_in[2];
  const float* gain = (const float*)d_in[3];

  float* out_attn = (float*)d_out;                       // (B,S,D) f32
  float* out_vflat = out_attn + (size_t)B_ * S_ * D_;    // (H*B,S,HD) f32

  uint8_t* w = (uint8_t*)d_ws;
  u16* xb     = (u16*)(w);                      // 16,777,216 B
  u16* wqkvb  = (u16*)(w + 16777216);           // 12,582,912 B
  u16* woutb  = (u16*)(w + 29360128);           //  8,388,608 B
  float* proj = (float*)(w + 37748736);         // 50,331,648 B
  u16* Qn     = (u16*)(w + 88080384);           // 16,777,216 B
  u16* Kn     = (u16*)(w + 104857600);          //  4,194,304 B
  u16* Vt     = (u16*)(w + 109051904);          //  4,194,304 B
  u16* attnb  = (u16*)(w + 113246208);          // 16,777,216 B
  float* tc   = (float*)(w + 130023424);        //    262,144 B
  float* ts   = (float*)(w + 130285568);        //    262,144 B
  // total: 130,547,712 B

  pack_bf16<<<4096, 256, 0, stream>>>(x, xb, B_ * S_ * D_);
  pack_bf16<<<3072, 256, 0, stream>>>(wqkv, wqkvb, PROJN * D_);
  pack_bf16<<<2048, 256, 0, stream>>>(wout, woutb, D_ * D_);
  rope_table<<<256, 256, 0, stream>>>(tc, ts);

  // proj = x @ w_qkv^T : (4096 x 3072)
  gemm_bt<<<(4096 / 128) * (3072 / 128), 256, 0, stream>>>(xb, wqkvb, proj,
                                                           4096, PROJN, 2048);
  rope_norm<<<(B_ * S_ * 40) / 4, 256, 0, stream>>>(proj, tc, ts, gain, Qn, Kn);
  vtrans<<<B_ * KVH_ * (S_ / 64), 256, 0, stream>>>(proj, Vt, out_vflat);
  attn_fwd<<<B_ * H_ * (S_ / 64), 256, 0, stream>>>(Qn, Kn, Vt, attnb);
  // attn_out = attn @ w_out^T : (4096 x 2048)
  gemm_bt<<<(4096 / 128) * (2048 / 128), 256, 0, stream>>>(attnb, woutb,
                                                           out_attn, 4096,
                                                           2048, 2048);
}

// Round 5
// 318.355 us; speedup vs baseline: 1.2101x; 1.1252x over previous
//
#include <hip/hip_runtime.h>
#include <hip/hip_bf16.h>
#include <cstdint>
#include <cstddef>

#define B_ 2
#define S_ 2048
#define D_ 2048
#define H_ 32
#define KVH_ 8
#define HD_ 64
#define PROJN 3072   // Q_OUT(2048) + 2*KV_OUT(512)

typedef unsigned short u16;
typedef unsigned int u32;
typedef __attribute__((ext_vector_type(8))) short short8;
typedef __attribute__((ext_vector_type(4))) short short4v;
typedef __attribute__((ext_vector_type(4))) float f32x4;

__device__ __forceinline__ u16 f2bf(float f) {
  __hip_bfloat16 h = __float2bfloat16(f);
  return *reinterpret_cast<u16*>(&h);
}

#define GLDS16(g, l)                                                           \
  __builtin_amdgcn_global_load_lds(                                            \
      (const __attribute__((address_space(1))) void*)(g),                      \
      (__attribute__((address_space(3))) void*)(l), 16, 0, 0)

// ---------------- pack f32 -> bf16 ----------------
__global__ __launch_bounds__(256) void pack_bf16(const float* __restrict__ in,
                                                 u16* __restrict__ out, int n) {
  int i = (blockIdx.x * 256 + threadIdx.x) * 8;
  if (i >= n) return;
  const float4* p = reinterpret_cast<const float4*>(in + i);
  float4 a = p[0], b = p[1];
  union { short8 v; u16 u[8]; } r;
  r.u[0] = f2bf(a.x); r.u[1] = f2bf(a.y); r.u[2] = f2bf(a.z); r.u[3] = f2bf(a.w);
  r.u[4] = f2bf(b.x); r.u[5] = f2bf(b.y); r.u[6] = f2bf(b.z); r.u[7] = f2bf(b.w);
  *reinterpret_cast<short8*>(out + i) = r.v;
}

// ---------------- rope cos/sin table ----------------
__global__ __launch_bounds__(256) void rope_table(float* __restrict__ tc,
                                                  float* __restrict__ ts) {
  int i = blockIdx.x * 256 + threadIdx.x;  // S_*32
  int s = i >> 5, j = i & 31;
  float e = (float)(2 * j) / 64.0f;
  float inv_freq = 1.0f / powf(10000.0f, e);
  float ang = (float)s * inv_freq;
  tc[i] = cosf(ang);
  ts[i] = sinf(ang);
}

// ---------------- bf16 GEMM: C[M,N] = A[M,K] * Bw[N,K]^T ----------------
__global__ __launch_bounds__(256) void gemm_bt(const u16* __restrict__ A,
                                               const u16* __restrict__ Bw,
                                               float* __restrict__ C, int M,
                                               int N, int K) {
  __shared__ u16 As[128 * 64];
  __shared__ u16 Bs[128 * 64];
  const int tid = threadIdx.x;
  const int lane = tid & 63;
  const int wave = tid >> 6;
  const int ntile = N >> 7;
  const int m0 = (blockIdx.x / ntile) << 7;
  const int n0 = (blockIdx.x % ntile) << 7;
  const int wr = (wave >> 1) << 6;
  const int wc = (wave & 1) << 6;
  const int arow = lane & 15;
  const int kgrp = lane >> 4;

  const f32x4 zero4 = {0.f, 0.f, 0.f, 0.f};
  f32x4 acc[4][4];
#pragma unroll
  for (int m = 0; m < 4; m++)
#pragma unroll
    for (int n = 0; n < 4; n++) acc[m][n] = zero4;

  int srow[4], sslot[4];
#pragma unroll
  for (int i = 0; i < 4; i++) {
    int c = i * 256 + tid;
    srow[i] = c >> 3;
    sslot[i] = (c & 7) ^ (srow[i] & 7);  // inverse-swizzled source slot
  }

  auto stage = [&](int kt) {
    const int k0 = kt << 6;
#pragma unroll
    for (int i = 0; i < 4; i++) {
      const u16* ga = A + (size_t)(m0 + srow[i]) * K + k0 + sslot[i] * 8;
      GLDS16(ga, As + (i * 256 + tid) * 8);
    }
#pragma unroll
    for (int i = 0; i < 4; i++) {
      const u16* gb = Bw + (size_t)(n0 + srow[i]) * K + k0 + sslot[i] * 8;
      GLDS16(gb, Bs + (i * 256 + tid) * 8);
    }
  };

  const int KT = K >> 6;
  stage(0);
  for (int kt = 0;; kt++) {
    __syncthreads();  // staging drained (compiler emits vmcnt(0) before barrier)
#pragma unroll
    for (int ks = 0; ks < 2; ks++) {
      const int sd = ks * 4 + kgrp;
      short8 a[4], b[4];
#pragma unroll
      for (int m = 0; m < 4; m++) {
        int r = wr + m * 16 + arow;
        a[m] = *reinterpret_cast<const short8*>(As + r * 64 + ((sd ^ (r & 7)) << 3));
      }
#pragma unroll
      for (int n = 0; n < 4; n++) {
        int r = wc + n * 16 + arow;
        b[n] = *reinterpret_cast<const short8*>(Bs + r * 64 + ((sd ^ (r & 7)) << 3));
      }
#pragma unroll
      for (int m = 0; m < 4; m++)
#pragma unroll
        for (int n = 0; n < 4; n++)
          acc[m][n] = __builtin_amdgcn_mfma_f32_16x16x32_bf16(a[m], b[n], acc[m][n], 0, 0, 0);
    }
    if (kt + 1 == KT) break;
    __syncthreads();
    stage(kt + 1);
  }

  const int crow = kgrp * 4;
#pragma unroll
  for (int m = 0; m < 4; m++) {
#pragma unroll
    for (int n = 0; n < 4; n++) {
      float* cp = C + (size_t)(m0 + wr + m * 16 + crow) * N + n0 + wc + n * 16 + arow;
#pragma unroll
      for (int r = 0; r < 4; r++) cp[(size_t)r * N] = acc[m][n][r];
    }
  }
}

// ---------------- RoPE + RMSNorm for Q and K ----------------
// one wave per (b, s, head'), head' in [0,40): 0..31 Q heads, 32..39 K heads
__global__ __launch_bounds__(256) void rope_norm(
    const float* __restrict__ proj, const float* __restrict__ tc,
    const float* __restrict__ ts, const float* __restrict__ gain,
    u16* __restrict__ Qn, u16* __restrict__ Kn) {
  int wid = (blockIdx.x * 256 + threadIdx.x) >> 6;  // B_*S_*40 waves
  int lane = threadIdx.x & 63;
  int hh = wid % 40;
  int bs = wid / 40;  // b*S_ + s
  int s = bs & (S_ - 1);
  int b = bs >> 11;
  int off = hh < 32 ? hh * 64 + lane : 2048 + (hh - 32) * 64 + lane;
  float val = proj[(size_t)bs * PROJN + off];
  int j = lane & 31;
  float c = tc[s * 32 + j], sn = ts[s * 32 + j];
  float partner = __shfl_xor(val, 32);
  float out = lane < 32 ? val * c - partner * sn : val * c + partner * sn;
  float ss = out * out;
#pragma unroll
  for (int m = 32; m >= 1; m >>= 1) ss += __shfl_xor(ss, m);
  float inv = rsqrtf(ss * (1.0f / 64.0f) + 1e-6f);
  float g = hh < 32 ? gain[0] : 1.0f;
  u16 ub = f2bf(out * inv * g);
  if (hh < 32)
    Qn[(((size_t)(b * H_ + hh)) * S_ + s) * HD_ + lane] = ub;
  else
    Kn[(((size_t)(b * KVH_ + (hh - 32))) * S_ + s) * HD_ + lane] = ub;
}

// ---------------- V: transpose to (B,KVH,HD,S) bf16 + V_flat f32 output ----------------
__global__ __launch_bounds__(256) void vtrans(const float* __restrict__ proj,
                                              u16* __restrict__ Vt,
                                              float* __restrict__ Vout) {
  __shared__ float tile[64][65];
  const int bid = blockIdx.x;  // B_*KVH_*(S_/64)
  const int st = bid & 31;
  const int s0 = st << 6;
  const int kvh = (bid >> 5) & 7;
  const int b = bid >> 8;
  const int t = threadIdx.x;
  const int sr = t >> 2;
  const int d0 = (t & 3) << 4;
  const float* src = proj + ((size_t)(b * S_ + s0 + sr)) * PROJN + 2560 + kvh * 64 + d0;
  float v[16];
#pragma unroll
  for (int i = 0; i < 16; i += 4) {
    float4 x = *reinterpret_cast<const float4*>(src + i);
    v[i] = x.x; v[i + 1] = x.y; v[i + 2] = x.z; v[i + 3] = x.w;
  }
  // V_flat output: rows h*B+b, 4 repeated heads (scale rsqrt(1+1e-8) == 1.0f exactly)
#pragma unroll
  for (int hh = 0; hh < 4; hh++) {
    int hq = kvh * 4 + hh;
    float* dst = Vout + (((size_t)(hq * B_ + b)) * S_ + s0 + sr) * HD_ + d0;
#pragma unroll
    for (int i = 0; i < 16; i += 4)
      *reinterpret_cast<float4*>(dst + i) = make_float4(v[i], v[i + 1], v[i + 2], v[i + 3]);
  }
#pragma unroll
  for (int i = 0; i < 16; i++) tile[sr][d0 + i] = v[i];
  __syncthreads();
  const int d = t >> 2;
  const int sc = (t & 3) << 4;
  union { short8 v8; u16 u[8]; } o0, o1;
#pragma unroll
  for (int i = 0; i < 8; i++) o0.u[i] = f2bf(tile[sc + i][d]);
#pragma unroll
  for (int i = 0; i < 8; i++) o1.u[i] = f2bf(tile[sc + 8 + i][d]);
  u16* dst = Vt + (((size_t)(b * KVH_ + kvh)) * HD_ + d) * S_ + s0 + sc;
  *reinterpret_cast<short8*>(dst) = o0.v8;
  *reinterpret_cast<short8*>(dst + 8) = o1.v8;
}

// ---------------- flash attention (causal, GQA) ----------------
// Block = (b, kvh, 32-row q-tile). Wave w = head kvh*4+w, owns 32 q-rows
// (2 Q-frags). K/V double-buffered in LDS, ONE barrier per KV tile, stage
// issued before compute (T3 2-phase). Swapped-operand MFMA as round 4:
// S^T = mfma(K,Q), O^T = mfma(V^T,P^T); lane&15 owns one q-row per frag.
__global__ __launch_bounds__(256, 3) void attn_fwd(const u16* __restrict__ Qn,
                                                   const u16* __restrict__ Kn,
                                                   const u16* __restrict__ Vt,
                                                   u16* __restrict__ Aout) {
  __shared__ u16 Ks[2][64 * 64];
  __shared__ u16 Vs[2][64 * 64];
  __shared__ u16 Ps[4][16 * 64];
  const int bid = blockIdx.x;          // B_*KVH_*64
  const int u = bid & 63;
  const int qt = (u & 1) ? (63 - (u >> 1)) : (u >> 1);  // long/short pairing
  const int kvh = (bid >> 6) & 7;
  const int b = bid >> 9;
  const int q0 = qt << 5;
  const int tid = threadIdx.x;
  const int lane = tid & 63;
  const int wave = tid >> 6;
  const int h = kvh * 4 + wave;        // this wave's Q head
  const int ql = lane & 15;
  const int g = lane >> 4;
  const float SCL2E = 0.125f * 1.44269504088896340736f;

  // Q frags: rows q0+16f+ql of head h, d-halves ks
  const u16* qbase = Qn + (((size_t)(b * H_ + h)) * S_ + q0 + ql) * HD_;
  short8 qa[2][2];
  qa[0][0] = *reinterpret_cast<const short8*>(qbase + g * 8);
  qa[0][1] = *reinterpret_cast<const short8*>(qbase + 32 + g * 8);
  qa[1][0] = *reinterpret_cast<const short8*>(qbase + 16 * HD_ + g * 8);
  qa[1][1] = *reinterpret_cast<const short8*>(qbase + 16 * HD_ + 32 + g * 8);

  const f32x4 zero4 = {0.f, 0.f, 0.f, 0.f};
  f32x4 oacc[4][2];
#pragma unroll
  for (int dn = 0; dn < 4; dn++)
#pragma unroll
    for (int f = 0; f < 2; f++) oacc[dn][f] = zero4;
  float mrun[2] = {-1e30f, -1e30f}, lrun[2] = {0.f, 0.f};

  const u16* kg = Kn + ((size_t)(b * KVH_ + kvh)) * S_ * HD_;
  const u16* vg = Vt + ((size_t)(b * KVH_ + kvh)) * HD_ * S_;

  const int c0 = tid, c1 = 256 + tid;
  const int r0 = c0 >> 3, sl0 = (c0 & 7) ^ (r0 & 7);
  const int r1 = c1 >> 3, sl1 = (c1 & 7) ^ (r1 & 7);

  u16* pw = Ps[wave];
  u32* pw32 = reinterpret_cast<u32*>(pw);
  const int xsw2 = (ql & 7) << 2;

  const int JT = (qt >> 1) + 1;

  auto stage = [&](int jt, int buf) {
    const int j0 = jt << 6;
    GLDS16(kg + (size_t)(j0 + r0) * HD_ + sl0 * 8, Ks[buf] + c0 * 8);
    GLDS16(kg + (size_t)(j0 + r1) * HD_ + sl1 * 8, Ks[buf] + c1 * 8);
    GLDS16(vg + (size_t)r0 * S_ + j0 + sl0 * 8, Vs[buf] + c0 * 8);
    GLDS16(vg + (size_t)r1 * S_ + j0 + sl1 * 8, Vs[buf] + c1 * 8);
  };

  stage(0, 0);
  __syncthreads();  // drain prologue stage
  int cur = 0;
  for (int jt = 0; jt < JT; jt++) {
    if (jt + 1 < JT) stage(jt + 1, cur ^ 1);  // issue next tile early (hidden)
    const int j0 = jt << 6;
    const u16* ksb = Ks[cur];
    const u16* vsb = Vs[cur];

    // S^T = K·Q^T for both q-frags (kf shared)
    f32x4 sc[4][2];
#pragma unroll
    for (int n = 0; n < 4; n++)
#pragma unroll
      for (int f = 0; f < 2; f++) sc[n][f] = zero4;
#pragma unroll
    for (int ks = 0; ks < 2; ks++) {
      const int sd = ks * 4 + g;
#pragma unroll
      for (int n = 0; n < 4; n++) {
        const int r = n * 16 + ql;
        short8 kf = *reinterpret_cast<const short8*>(ksb + r * 64 + ((sd ^ (r & 7)) << 3));
        sc[n][0] = __builtin_amdgcn_mfma_f32_16x16x32_bf16(kf, qa[0][ks], sc[n][0], 0, 0, 0);
        sc[n][1] = __builtin_amdgcn_mfma_f32_16x16x32_bf16(kf, qa[1][ks], sc[n][1], 0, 0, 0);
      }
    }

    // scale (log2 domain) + causal mask (only last tile can violate)
    const bool diag = (jt == JT - 1);
#pragma unroll
    for (int f = 0; f < 2; f++) {
      const int rowq = q0 + 16 * f + ql;
#pragma unroll
      for (int n = 0; n < 4; n++)
#pragma unroll
        for (int r = 0; r < 4; r++) {
          float v = sc[n][f][r] * SCL2E;
          if (diag && (j0 + n * 16 + 4 * g + r) > rowq) v = -1e30f;
          sc[n][f][r] = v;
        }
    }

    // online softmax per q-frag: per-lane over 16 + 2 shfl_xor reduces
    float alpha[2];
#pragma unroll
    for (int f = 0; f < 2; f++) {
      float tmax = -1e30f;
#pragma unroll
      for (int n = 0; n < 4; n++)
#pragma unroll
        for (int r = 0; r < 4; r++) tmax = fmaxf(tmax, sc[n][f][r]);
      tmax = fmaxf(tmax, __shfl_xor(tmax, 16));
      tmax = fmaxf(tmax, __shfl_xor(tmax, 32));
      const float mnew = fmaxf(mrun[f], tmax);
      alpha[f] = exp2f(mrun[f] - mnew);
      float sum = 0.f;
#pragma unroll
      for (int n = 0; n < 4; n++)
#pragma unroll
        for (int r = 0; r < 4; r++) {
          float p = exp2f(sc[n][f][r] - mnew);
          sc[n][f][r] = p;
          sum += p;
        }
      sum += __shfl_xor(sum, 16);
      sum += __shfl_xor(sum, 32);
      lrun[f] = lrun[f] * alpha[f] + sum;
      mrun[f] = mnew;
#pragma unroll
      for (int dn = 0; dn < 4; dn++)
#pragma unroll
        for (int r = 0; r < 4; r++) oacc[dn][f][r] *= alpha[f];
    }

    // P^T -> per-wave LDS (16-row buffer reused per frag; DS ops in-order)
    short8 pa[2][2];
#pragma unroll
    for (int f = 0; f < 2; f++) {
#pragma unroll
      for (int n = 0; n < 4; n++) {
        union { u32 w; u16 hh[2]; } c01, c23;
        c01.hh[0] = f2bf(sc[n][f][0]); c01.hh[1] = f2bf(sc[n][f][1]);
        c23.hh[0] = f2bf(sc[n][f][2]); c23.hh[1] = f2bf(sc[n][f][3]);
        const int idx = ql * 32 + (((n << 3) + (g << 1)) ^ xsw2);
        pw32[idx] = c01.w;
        pw32[idx + 1] = c23.w;
      }
#pragma unroll
      for (int ks = 0; ks < 2; ks++)
        pa[ks][f] = *reinterpret_cast<const short8*>(
            pw + ql * 64 + ((32 * ks + 8 * g) ^ (xsw2 << 1)));
    }

    // O^T += V^T · P^T (vf shared across both frags)
#pragma unroll
    for (int ks = 0; ks < 2; ks++) {
      const int sd = ks * 4 + g;
#pragma unroll
      for (int dn = 0; dn < 4; dn++) {
        const int vr = dn * 16 + ql;
        short8 vf = *reinterpret_cast<const short8*>(vsb + vr * 64 + ((sd ^ (vr & 7)) << 3));
        oacc[dn][0] = __builtin_amdgcn_mfma_f32_16x16x32_bf16(vf, pa[ks][0], oacc[dn][0], 0, 0, 0);
        oacc[dn][1] = __builtin_amdgcn_mfma_f32_16x16x32_bf16(vf, pa[ks][1], oacc[dn][1], 0, 0, 0);
      }
    }

    __syncthreads();  // stage(jt+1) drained + all reads of buf[cur] done
    cur ^= 1;
  }

#pragma unroll
  for (int f = 0; f < 2; f++) {
    const float il = 1.0f / lrun[f];
    const int rowq = q0 + 16 * f + ql;
#pragma unroll
    for (int dn = 0; dn < 4; dn++) {
      union { short4v v; u16 uu[4]; } o;
#pragma unroll
      for (int r = 0; r < 4; r++) o.uu[r] = f2bf(oacc[dn][f][r] * il);
      u16* dst = Aout + ((size_t)b * S_ + rowq) * D_ + h * HD_ + dn * 16 + 4 * g;
      *reinterpret_cast<short4v*>(dst) = o.v;
    }
  }
}

// ---------------- launcher ----------------
extern "C" void kernel_launch(void* const* d_in, const int* in_sizes, int n_in,
                              void* d_out, int out_size, void* d_ws,
                              size_t ws_size, hipStream_t stream) {
  const float* x = (const float*)d_in[0];
  const float* wqkv = (const float*)d_in[1];
  const float* wout = (const float*)d_in[2];
  const float* gain = (const float*)d_in[3];

  float* out_attn = (float*)d_out;                       // (B,S,D) f32
  float* out_vflat = out_attn + (size_t)B_ * S_ * D_;    // (H*B,S,HD) f32

  uint8_t* w = (uint8_t*)d_ws;
  u16* xb     = (u16*)(w);                      // 16,777,216 B
  u16* wqkvb  = (u16*)(w + 16777216);           // 12,582,912 B
  u16* woutb  = (u16*)(w + 29360128);           //  8,388,608 B
  float* proj = (float*)(w + 37748736);         // 50,331,648 B
  u16* Qn     = (u16*)(w + 88080384);           // 16,777,216 B
  u16* Kn     = (u16*)(w + 104857600);          //  4,194,304 B
  u16* Vt     = (u16*)(w + 109051904);          //  4,194,304 B
  u16* attnb  = (u16*)(w + 113246208);          // 16,777,216 B
  float* tc   = (float*)(w + 130023424);        //    262,144 B
  float* ts   = (float*)(w + 130285568);        //    262,144 B
  // total: 130,547,712 B

  pack_bf16<<<4096, 256, 0, stream>>>(x, xb, B_ * S_ * D_);
  pack_bf16<<<3072, 256, 0, stream>>>(wqkv, wqkvb, PROJN * D_);
  pack_bf16<<<2048, 256, 0, stream>>>(wout, woutb, D_ * D_);
  rope_table<<<256, 256, 0, stream>>>(tc, ts);

  // proj = x @ w_qkv^T : (4096 x 3072)
  gemm_bt<<<(4096 / 128) * (3072 / 128), 256, 0, stream>>>(xb, wqkvb, proj,
                                                           4096, PROJN, 2048);
  rope_norm<<<(B_ * S_ * 40) / 4, 256, 0, stream>>>(proj, tc, ts, gain, Qn, Kn);
  vtrans<<<B_ * KVH_ * (S_ / 64), 256, 0, stream>>>(proj, Vt, out_vflat);
  attn_fwd<<<B_ * KVH_ * (S_ / 32), 256, 0, stream>>>(Qn, Kn, Vt, attnb);
  // attn_out = attn @ w_out^T : (4096 x 2048)
  gemm_bt<<<(4096 / 128) * (2048 / 128), 256, 0, stream>>>(attnb, woutb,
                                                           out_attn, 4096,
                                                           2048, 2048);
}